// Round 20
// baseline (49.554 us; speedup 1.0000x reference)
//
#include <hip/hip_runtime.h>
#include <hip/hip_bf16.h>

// ST-GCN spatial graph conv — swapped contraction, in-register two-stage MFMA.
// R20: 512 all-resident blocks (= 2 blocks/CU x 256 CU, one residency round,
// perfect balance: every CU gets exactly 2 blocks = 37.5 items). Wave wid
// processes G consecutive-t items (G=3 for wid<1408 else 2; 1408*3+2688*2=9600).
// Serial x-buffer reuse chain (R19-proven, 64 VGPR): item g+1's loads issue
// before item g's compute; item-1 loads fly under the gll mirror staging.
// Consecutive-t items: x windows overlap 75% (FETCH drop), out lines merge.
//
//   stage A (per n,t):  y[ci][32k+w] = sum_v x[n,ci,t,v] * A[k,v,w]
//       K-axis = v -> per-lane x frag = 8 consecutive floats (2 aligned f32x4),
//       d = t&3 dword phase via 4 pre-shifted Ahat images (all in the mirror).
//   stage B:  out[c][w] = sum_{k,ci} W[64k+c][ci] * y[ci][32k+w]
//       W2img pre-permuted so each lane's B-frag == its own stage-A acc values.
//   bias folded into boutT init image. Math bit-identical to R10/R13.

#define CIN   64
#define T_    300
#define V_    25
#define COUT  64

#define WS_W2 0        // 24576 B : bf16 W2img, 24 slabs of 1KB (lane-sliced)
#define WS_AH 24576    // 24576 B : bf16 AhatT4[d(4)][kw(96)][vp(32)]
#define WS_BO 49152    // 8192  B : f32  boutT[w(32)][c(64)]
#define WS_BYTES 57344

// LDS mirror: slab s at smem + s*1024, lane l's frag at + l*16
#define LDS_W2 0         // slabs  0..23 : (ct*6+kap)
#define LDS_AH 24576     // slabs 24..47 : (d*6+ni)
#define LDS_BO 49152     // slabs 48..55 : (ct*2+nt)
#define SMEM_BYTES 57344

typedef short  bf16x8 __attribute__((ext_vector_type(8)));
typedef float  f32x4  __attribute__((ext_vector_type(4)));

__device__ __forceinline__ unsigned short cvt_bf16(float f) {
    union { __hip_bfloat16 h; unsigned short u; } cv;
    cv.h = __float2bfloat16(f);
    return cv.u;
}
__device__ __forceinline__ unsigned pk2(float a, float b) {
    return (unsigned)cvt_bf16(a) | ((unsigned)cvt_bf16(b) << 16);
}
union fragu { bf16x8 v; unsigned u[4]; };

#define GLL16(g, s) __builtin_amdgcn_global_load_lds( \
    (const __attribute__((address_space(1))) void*)(g), \
    (__attribute__((address_space(3))) void*)(s), 16, 0, 0)

// ---------------- prepass: bake W2img / AhatT4 / boutT (identical to R10/R13) ----
__global__ void gcn_prep(const float* __restrict__ W, const float* __restrict__ bias,
                         const float* __restrict__ A, unsigned char* __restrict__ ws)
{
    const int tid = blockIdx.x * 256 + threadIdx.x;   // 4096 threads
    for (int i = tid; i < 4 * 6 * 64 * 8; i += 4096) {
        const int e = i & 7, lane = (i >> 3) & 63, ck = i >> 9;
        const int kap = ck % 6, ct = ck / 6;
        const int lr = lane & 15, lq = lane >> 4;
        const int row = (kap >> 1) * COUT + ct * 16 + lr;
        const int col = 32 * (kap & 1) + 16 * (e >> 2) + 4 * lq + (e & 3);
        reinterpret_cast<unsigned short*>(ws + WS_W2)[i] = cvt_bf16(W[row * CIN + col]);
    }
    for (int i = tid; i < 4 * 96 * 32; i += 4096) {
        const int vp = i & 31, kw = (i >> 5) % 96, dd = (i >> 5) / 96;
        const int k = kw >> 5, w = kw & 31, v = vp - dd;
        const float val = (v >= 0 && v < V_ && w < V_) ? A[(k * V_ + v) * V_ + w] : 0.f;
        reinterpret_cast<unsigned short*>(ws + WS_AH)[i] = cvt_bf16(val);
    }
    for (int i = tid; i < 32 * 64; i += 4096) {
        const int w = i >> 6, c = i & 63;
        float s = 0.f;
        if (w < V_) {
            for (int k = 0; k < 3; ++k) {
                float sa = 0.f;
                for (int v = 0; v < V_; ++v) sa += A[(k * V_ + v) * V_ + w];
                s += bias[k * COUT + c] * sa;
            }
        }
        reinterpret_cast<float*>(ws + WS_BO)[i] = s;
    }
}

// ---------------- main: 512 blocks x 8 waves; wave = 2-3 consecutive items ----
__global__ __launch_bounds__(512, 4) void gcn_main(
    const float* __restrict__ x, const unsigned char* __restrict__ ws,
    float* __restrict__ out)
{
    __shared__ __align__(16) unsigned char smem[SMEM_BYTES];

    const int tid = threadIdx.x;
    const int wv = tid >> 6, l = tid & 63, lr = l & 15, lq = l >> 4;
    const int wid = blockIdx.x * 8 + wv;              // 0..4095
    const bool g3 = wid < 1408;                       // 1408*3 + 2688*2 = 9600
    const int it0 = g3 ? 3 * wid : 2 * wid + 1408;    // contiguous item ranges

    // ---- issue x loads for item `it` into xa/xg
    auto loadx = [&](int it, f32x4 (&xa)[4], f32x4 (&xg)[4]) {
        const int n = it / T_, t = it % T_, d = t & 3;
        const float* xrow = x + (size_t)(n * CIN + lr) * (T_ * V_) + (t * V_ - d) + 8 * lq;
        #pragma unroll
        for (int mi = 0; mi < 4; ++mi) {
            const float* p = xrow + (size_t)mi * 16 * (T_ * V_);
            xa[mi] = *reinterpret_cast<const f32x4*>(p);
            // lq==3: vp=28..31 hits all-zero Ahat rows -> dup of first chunk
            xg[mi] = *reinterpret_cast<const f32x4*>(p + (lq < 3 ? 4 : 0));
        }
    };
    auto cvtx = [&](const f32x4 (&xa)[4], const f32x4 (&xg)[4], bf16x8 (&xf)[4]) {
        #pragma unroll
        for (int mi = 0; mi < 4; ++mi) {
            fragu f;
            f.u[0] = pk2(xa[mi][0], xa[mi][1]);
            f.u[1] = pk2(xa[mi][2], xa[mi][3]);
            f.u[2] = pk2(xg[mi][0], xg[mi][1]);
            f.u[3] = pk2(xg[mi][2], xg[mi][3]);
            xf[mi] = f.v;
        }
    };
    // ---- compute + store one item (reads mirror + xf only)
    auto run = [&](int it, const bf16x8 (&xf)[4]) {
        const int n = it / T_, t = it % T_, d = t & 3;
        f32x4 oacc[4][2];
        #pragma unroll
        for (int ct = 0; ct < 4; ++ct)
            #pragma unroll
            for (int nt = 0; nt < 2; ++nt)
                oacc[ct][nt] = *reinterpret_cast<const f32x4*>(
                    smem + LDS_BO + ((ct * 2 + nt) << 10) + l * 16);
        #pragma unroll
        for (int k = 0; k < 3; ++k) {
            bf16x8 ahf[2];
            #pragma unroll
            for (int j = 0; j < 2; ++j)
                ahf[j] = *reinterpret_cast<const bf16x8*>(
                    smem + LDS_AH + ((d * 6 + 2 * k + j) << 10) + l * 16);
            f32x4 y[4][2];
            #pragma unroll
            for (int mi = 0; mi < 4; ++mi)
                #pragma unroll
                for (int j = 0; j < 2; ++j)
                    y[mi][j] = (f32x4){0.f, 0.f, 0.f, 0.f};
            #pragma unroll
            for (int j = 0; j < 2; ++j)
                #pragma unroll
                for (int mi = 0; mi < 4; ++mi)
                    y[mi][j] = __builtin_amdgcn_mfma_f32_16x16x32_bf16(
                        xf[mi], ahf[j], y[mi][j], 0, 0, 0);
            #pragma unroll
            for (int kl = 0; kl < 2; ++kl) {
                bf16x8 w2f[4];
                #pragma unroll
                for (int ct = 0; ct < 4; ++ct)
                    w2f[ct] = *reinterpret_cast<const bf16x8*>(
                        smem + LDS_W2 + ((ct * 6 + 2 * k + kl) << 10) + l * 16);
                #pragma unroll
                for (int nt = 0; nt < 2; ++nt) {
                    fragu bb;
                    bb.u[0] = pk2(y[2 * kl][nt][0],     y[2 * kl][nt][1]);
                    bb.u[1] = pk2(y[2 * kl][nt][2],     y[2 * kl][nt][3]);
                    bb.u[2] = pk2(y[2 * kl + 1][nt][0], y[2 * kl + 1][nt][1]);
                    bb.u[3] = pk2(y[2 * kl + 1][nt][2], y[2 * kl + 1][nt][3]);
                    #pragma unroll
                    for (int ct = 0; ct < 4; ++ct)
                        oacc[ct][nt] = __builtin_amdgcn_mfma_f32_16x16x32_bf16(
                            w2f[ct], bb.v, oacc[ct][nt], 0, 0, 0);
                }
            }
        }
        float* ob = out + ((size_t)(n * COUT) * T_ + t) * V_;
        #pragma unroll
        for (int ct = 0; ct < 4; ++ct) {
            #pragma unroll
            for (int r = 0; r < 4; ++r) {
                const int c = 16 * ct + 4 * lq + r;
                float* op = ob + (size_t)c * (T_ * V_);
                op[lr] = oacc[ct][0][r];
                if (lr < 9) op[16 + lr] = oacc[ct][1][r];
            }
        }
    };

    // ---- item-0 x loads: fly during mirror staging
    f32x4 xa[4], xg[4];
    loadx(it0, xa, xg);

    // ---- stage invariant images ws -> LDS mirror: 56 slabs, 7 gll per wave
    for (int s = wv; s < 56; s += 8) {
        const unsigned char* src;
        if (s < 24) {
            src = ws + WS_W2 + s * 1024 + l * 16;                       // linear
        } else if (s < 48) {
            src = ws + WS_AH + (s - 24) * 1024 + 64 * lr + 16 * lq;     // frag perm
        } else {
            const int i2 = s - 48, nt = i2 & 1, ct = i2 >> 1;
            src = ws + WS_BO + (16 * nt + lr) * 256 + 64 * ct + 16 * lq;
        }
        GLL16(src, smem + s * 1024);
    }
    __builtin_amdgcn_sched_barrier(0);   // nothing sinks below this point

    // ---- cvt item-0 (waits on its loads; gll still in flight), prefetch item-1
    bf16x8 xf[4];
    cvtx(xa, xg, xf);
    loadx(it0 + 1, xa, xg);              // into freed buffer, flies across barrier
    __builtin_amdgcn_sched_barrier(0);

    __syncthreads();   // drains gll queue; LDS mirror complete

    run(it0, xf);                        // item 0 (item-1 loads underneath)

    cvtx(xa, xg, xf);                    // item 1 frags; buffer freed
    if (g3) loadx(it0 + 2, xa, xg);      // prefetch item 2 under item-1 compute
    __builtin_amdgcn_sched_barrier(0);
    run(it0 + 1, xf);                    // item 1

    if (g3) {
        cvtx(xa, xg, xf);
        run(it0 + 2, xf);                // item 2
    }
}

extern "C" void kernel_launch(void* const* d_in, const int* in_sizes, int n_in,
                              void* d_out, int out_size, void* d_ws, size_t ws_size,
                              hipStream_t stream) {
    const float* x    = (const float*)d_in[0];
    const float* W    = (const float*)d_in[1];
    const float* bias = (const float*)d_in[2];
    const float* A    = (const float*)d_in[3];
    float* out = (float*)d_out;
    unsigned char* ws = (unsigned char*)d_ws;   // needs WS_BYTES = 57344

    hipLaunchKernelGGL(gcn_prep, dim3(16), dim3(256), 0, stream, W, bias, A, ws);
    hipLaunchKernelGGL(gcn_main, dim3(512), dim3(512), 0, stream, x, ws, out);
}

// Round 21
// 37.336 us; speedup vs baseline: 1.3272x; 1.3272x over previous
//
#include <hip/hip_runtime.h>
#include <hip/hip_bf16.h>

// ST-GCN spatial graph conv — swapped contraction, in-register two-stage MFMA.
// R21 = R13 (best, 38.4us) + XCD-aware block swizzle: hw block b -> logical
// (b%8)*150 + b/8 (bijective, 1200%8==0). Each XCD owns 150 consecutive-t
// logical blocks; at any instant its active x window (~512 t-items ~ 3.3MB)
// fits the 4MB per-XCD L2, so the 75%-overlapping x loads of neighbor items
// hit L2 (~200cyc) instead of L3 (~350cyc). Everything else byte-identical R13.
//
//   stage A (per n,t):  y[ci][32k+w] = sum_v x[n,ci,t,v] * A[k,v,w]
//       K-axis = v -> per-lane x frag = 8 consecutive floats (2 aligned f32x4),
//       d = t&3 dword phase handled by 4 pre-shifted Ahat images (all in mirror).
//   stage B:  out[c][w] = sum_{k,ci} W[64k+c][ci] * y[ci][32k+w]
//       W2img pre-permuted so each lane's B-frag == its own stage-A acc values.
//   bias folded into boutT init image. Math bit-identical to R10/R13.

#define CIN   64
#define T_    300
#define V_    25
#define COUT  64

#define WS_W2 0        // 24576 B : bf16 W2img, 24 slabs of 1KB (lane-sliced)
#define WS_AH 24576    // 24576 B : bf16 AhatT4[d(4)][kw(96)][vp(32)]
#define WS_BO 49152    // 8192  B : f32  boutT[w(32)][c(64)]
#define WS_BYTES 57344

// LDS mirror: slab s at smem + s*1024, lane l's frag at + l*16
#define LDS_W2 0         // slabs  0..23 : (ct*6+kap)
#define LDS_AH 24576     // slabs 24..47 : (d*6+ni)
#define LDS_BO 49152     // slabs 48..55 : (ct*2+nt)
#define SMEM_BYTES 57344

typedef short  bf16x8 __attribute__((ext_vector_type(8)));
typedef float  f32x4  __attribute__((ext_vector_type(4)));

__device__ __forceinline__ unsigned short cvt_bf16(float f) {
    union { __hip_bfloat16 h; unsigned short u; } cv;
    cv.h = __float2bfloat16(f);
    return cv.u;
}
__device__ __forceinline__ unsigned pk2(float a, float b) {
    return (unsigned)cvt_bf16(a) | ((unsigned)cvt_bf16(b) << 16);
}
union fragu { bf16x8 v; unsigned u[4]; };

#define GLL16(g, s) __builtin_amdgcn_global_load_lds( \
    (const __attribute__((address_space(1))) void*)(g), \
    (__attribute__((address_space(3))) void*)(s), 16, 0, 0)

// ---------------- prepass: bake W2img / AhatT4 / boutT (identical to R10/R13) ----
__global__ void gcn_prep(const float* __restrict__ W, const float* __restrict__ bias,
                         const float* __restrict__ A, unsigned char* __restrict__ ws)
{
    const int tid = blockIdx.x * 256 + threadIdx.x;   // 4096 threads
    for (int i = tid; i < 4 * 6 * 64 * 8; i += 4096) {
        const int e = i & 7, lane = (i >> 3) & 63, ck = i >> 9;
        const int kap = ck % 6, ct = ck / 6;
        const int lr = lane & 15, lq = lane >> 4;
        const int row = (kap >> 1) * COUT + ct * 16 + lr;
        const int col = 32 * (kap & 1) + 16 * (e >> 2) + 4 * lq + (e & 3);
        reinterpret_cast<unsigned short*>(ws + WS_W2)[i] = cvt_bf16(W[row * CIN + col]);
    }
    for (int i = tid; i < 4 * 96 * 32; i += 4096) {
        const int vp = i & 31, kw = (i >> 5) % 96, dd = (i >> 5) / 96;
        const int k = kw >> 5, w = kw & 31, v = vp - dd;
        const float val = (v >= 0 && v < V_ && w < V_) ? A[(k * V_ + v) * V_ + w] : 0.f;
        reinterpret_cast<unsigned short*>(ws + WS_AH)[i] = cvt_bf16(val);
    }
    for (int i = tid; i < 32 * 64; i += 4096) {
        const int w = i >> 6, c = i & 63;
        float s = 0.f;
        if (w < V_) {
            for (int k = 0; k < 3; ++k) {
                float sa = 0.f;
                for (int v = 0; v < V_; ++v) sa += A[(k * V_ + v) * V_ + w];
                s += bias[k * COUT + c] * sa;
            }
        }
        reinterpret_cast<float*>(ws + WS_BO)[i] = s;
    }
}

// ---------------- main: 1 wave = 1 (n,t); 8 waves/block share LDS mirror ----
__global__ __launch_bounds__(512, 4) void gcn_main(
    const float* __restrict__ x, const unsigned char* __restrict__ ws,
    float* __restrict__ out)
{
    __shared__ __align__(16) unsigned char smem[SMEM_BYTES];

    const int tid = threadIdx.x;
    const int wv = tid >> 6, l = tid & 63, lr = l & 15, lq = l >> 4;
    // XCD swizzle: hw block b -> logical (b%8)*150 + b/8 (bijective, 1200%8==0).
    // Consecutive logical blocks (adjacent t) land on the SAME XCD -> x-window
    // overlap served from that XCD's L2 instead of L3.
    const int bxl = (blockIdx.x & 7) * 150 + (blockIdx.x >> 3);
    const int gid = bxl * 8 + wv;                     // 0..9599
    const int n = gid / T_, t = gid % T_;
    const int d = t & 3;                              // wave-uniform dword phase
    const int qoff = t * V_ - d;                      // 16B-aligned float offset

    // ---- per-output x loads (8 f32x4, L2/L3) — issued FIRST, fly during staging
    const float* xrow = x + (size_t)(n * CIN + lr) * (T_ * V_) + qoff + 8 * lq;
    f32x4 xa[4], xg[4];
    #pragma unroll
    for (int mi = 0; mi < 4; ++mi) {
        const float* p = xrow + (size_t)mi * 16 * (T_ * V_);
        xa[mi] = *reinterpret_cast<const f32x4*>(p);
        // lq==3: vp=28..31 hits all-zero Ahat rows -> dup of first chunk
        xg[mi] = *reinterpret_cast<const f32x4*>(p + (lq < 3 ? 4 : 0));
    }

    // ---- stage invariant images ws -> LDS mirror: 56 slabs, 7 gll per wave.
    //      dest = uniform slab base (+ lane*16 by HW); src = per-lane address.
    #pragma unroll
    for (int s = wv; s < 56; s += 8) {
        const unsigned char* src;
        if (s < 24) {
            src = ws + WS_W2 + s * 1024 + l * 16;                       // linear
        } else if (s < 48) {
            src = ws + WS_AH + (s - 24) * 1024 + 64 * lr + 16 * lq;     // frag perm
        } else {
            const int i2 = s - 48, nt = i2 & 1, ct = i2 >> 1;
            src = ws + WS_BO + (16 * nt + lr) * 256 + 64 * ct + 16 * lq;
        }
        GLL16(src, smem + s * 1024);
    }
    __builtin_amdgcn_sched_barrier(0);   // nothing sinks below this point

    // ---- convert x to bf16 A-frags (waits only on the 8 x loads; gll in flight)
    bf16x8 xf[4];
    #pragma unroll
    for (int mi = 0; mi < 4; ++mi) {
        fragu f;
        f.u[0] = pk2(xa[mi][0], xa[mi][1]);
        f.u[1] = pk2(xa[mi][2], xa[mi][3]);
        f.u[2] = pk2(xg[mi][0], xg[mi][1]);
        f.u[3] = pk2(xg[mi][2], xg[mi][3]);
        xf[mi] = f.v;
    }

    __syncthreads();   // drains gll queue; LDS mirror complete

    // ---- oacc init from bout slabs (lane-linear ds_read_b128, conflict-free)
    f32x4 oacc[4][2];
    #pragma unroll
    for (int ct = 0; ct < 4; ++ct)
        #pragma unroll
        for (int nt = 0; nt < 2; ++nt)
            oacc[ct][nt] = *reinterpret_cast<const f32x4*>(
                smem + LDS_BO + ((ct * 2 + nt) << 10) + l * 16);

    // ---- fused stages per k: stage A (8 MFMA) -> handoff -> stage B (16 MFMA)
    #pragma unroll
    for (int k = 0; k < 3; ++k) {
        bf16x8 ahf[2];
        #pragma unroll
        for (int j = 0; j < 2; ++j)
            ahf[j] = *reinterpret_cast<const bf16x8*>(
                smem + LDS_AH + ((d * 6 + 2 * k + j) << 10) + l * 16);

        f32x4 y[4][2];
        #pragma unroll
        for (int mi = 0; mi < 4; ++mi)
            #pragma unroll
            for (int j = 0; j < 2; ++j)
                y[mi][j] = (f32x4){0.f, 0.f, 0.f, 0.f};
        #pragma unroll
        for (int j = 0; j < 2; ++j)
            #pragma unroll
            for (int mi = 0; mi < 4; ++mi)
                y[mi][j] = __builtin_amdgcn_mfma_f32_16x16x32_bf16(
                    xf[mi], ahf[j], y[mi][j], 0, 0, 0);

        // handoff: B-frag[e] = bf16(y[2kl + (e>>2)][nt][e&3]) — all lane-local
        #pragma unroll
        for (int kl = 0; kl < 2; ++kl) {
            bf16x8 w2f[4];
            #pragma unroll
            for (int ct = 0; ct < 4; ++ct)
                w2f[ct] = *reinterpret_cast<const bf16x8*>(
                    smem + LDS_W2 + ((ct * 6 + 2 * k + kl) << 10) + l * 16);
            #pragma unroll
            for (int nt = 0; nt < 2; ++nt) {
                fragu bb;
                bb.u[0] = pk2(y[2 * kl][nt][0],     y[2 * kl][nt][1]);
                bb.u[1] = pk2(y[2 * kl][nt][2],     y[2 * kl][nt][3]);
                bb.u[2] = pk2(y[2 * kl + 1][nt][0], y[2 * kl + 1][nt][1]);
                bb.u[3] = pk2(y[2 * kl + 1][nt][2], y[2 * kl + 1][nt][3]);
                #pragma unroll
                for (int ct = 0; ct < 4; ++ct)
                    oacc[ct][nt] = __builtin_amdgcn_mfma_f32_16x16x32_bf16(
                        w2f[ct], bb.v, oacc[ct][nt], 0, 0, 0);
            }
        }
    }

    // ---- store: lane holds out[c = 16ct+4lq+r][w = 16nt+lr]
    float* ob = out + ((size_t)(n * COUT) * T_ + t) * V_;
    #pragma unroll
    for (int ct = 0; ct < 4; ++ct) {
        #pragma unroll
        for (int r = 0; r < 4; ++r) {
            const int c = 16 * ct + 4 * lq + r;
            float* op = ob + (size_t)c * (T_ * V_);
            op[lr] = oacc[ct][0][r];
            if (lr < 9) op[16 + lr] = oacc[ct][1][r];
        }
    }
}

extern "C" void kernel_launch(void* const* d_in, const int* in_sizes, int n_in,
                              void* d_out, int out_size, void* d_ws, size_t ws_size,
                              hipStream_t stream) {
    const float* x    = (const float*)d_in[0];
    const float* W    = (const float*)d_in[1];
    const float* bias = (const float*)d_in[2];
    const float* A    = (const float*)d_in[3];
    float* out = (float*)d_out;
    unsigned char* ws = (unsigned char*)d_ws;   // needs WS_BYTES = 57344

    hipLaunchKernelGGL(gcn_prep, dim3(16), dim3(256), 0, stream, W, bias, A, ws);
    hipLaunchKernelGGL(gcn_main, dim3(1200), dim3(512), 0, stream, x, ws, out);
}